// Round 1
// baseline (859.423 us; speedup 1.0000x reference)
//
#include <hip/hip_runtime.h>
#include <hip/hip_bf16.h>

typedef _Float16 f16x8 __attribute__((ext_vector_type(8)));
typedef float f32x4 __attribute__((ext_vector_type(4)));

__device__ __forceinline__ void async16(const _Float16* g, _Float16* l) {
  __builtin_amdgcn_global_load_lds(
      (const __attribute__((address_space(1))) unsigned int*)g,
      (__attribute__((address_space(3))) unsigned int*)l, 16, 0, 0);
}

__device__ __forceinline__ float tanh_fast(float x) {
  float e = __expf(2.0f * x);
  return 1.0f - 2.0f * __builtin_amdgcn_rcpf(e + 1.0f);
}
__device__ __forceinline__ float sigmoid_fast(float x) {
  return __builtin_amdgcn_rcpf(1.0f + __expf(-x));
}

// ---------------- K0: transpose + fp32 -> fp16 convert ----------------
// in: [Z][R][C] fp32  ->  out: [Z][C][R] fp16
__global__ __launch_bounds__(256) void transpose_cvt(const float* __restrict__ in,
                                                     _Float16* __restrict__ out,
                                                     int R, int C) {
  __shared__ float tile[32][33];
  int z = blockIdx.z;
  in  += (size_t)z * R * C;
  out += (size_t)z * R * C;
  int r0 = blockIdx.x * 32, c0 = blockIdx.y * 32;
  int t = threadIdx.x;
  int cc = t & 31, rr8 = t >> 5;
#pragma unroll
  for (int p = 0; p < 4; ++p) {
    int r = rr8 + p * 8;
    tile[cc][r] = in[(size_t)(r0 + r) * C + c0 + cc];
  }
  __syncthreads();
  int rr = t & 31, cc8 = t >> 5;
#pragma unroll
  for (int p = 0; p < 4; ++p) {
    int c = cc8 + p * 8;
    out[(size_t)(c0 + c) * R + r0 + rr] = (_Float16)tile[c][rr];
  }
}

// ---------------- K1: ripple layer 1 ----------------
// x1[b,u] = tanh( sum_d sa[b,d]*V1t[u,d] + b1[u] ) * sigmoid(g1[u>>5])
__global__ __launch_bounds__(256) void k1_ripple1(
    const float* __restrict__ state, const float* __restrict__ action,
    const _Float16* __restrict__ v1t, const float* __restrict__ b1,
    const float* __restrict__ g1, _Float16* __restrict__ x1, int gro) {
  __shared__ __align__(16) _Float16 As[128 * 32];
  int bn = blockIdx.x;      // 0..7 col tile
  int bm = blockIdx.y;      // row tile within slice
  int t = threadIdx.x, w = t >> 6, l = t & 63, q = l >> 4, l15 = l & 15;
  int n0 = bn * 128, m0 = bm * 128;

  {  // stage sa tile [128][32] fp16 (concat state|action, converted)
    int r = t >> 1, half = t & 1;
    size_t grow = (size_t)(gro + m0 + r);
    float v[16];
    if (half == 0) {
      const float4* sp = (const float4*)(state + grow * 24);
      ((float4*)v)[0] = sp[0]; ((float4*)v)[1] = sp[1];
      ((float4*)v)[2] = sp[2]; ((float4*)v)[3] = sp[3];
    } else {
      const float4* sp = (const float4*)(state + grow * 24 + 16);
      ((float4*)v)[0] = sp[0]; ((float4*)v)[1] = sp[1];
      const float4* ap = (const float4*)(action + grow * 8);
      ((float4*)v)[2] = ap[0]; ((float4*)v)[3] = ap[1];
    }
    f16x8 h0, h1;
#pragma unroll
    for (int j = 0; j < 8; ++j) { h0[j] = (_Float16)v[j]; h1[j] = (_Float16)v[8 + j]; }
    *(f16x8*)&As[r * 32 + half * 16] = h0;
    *(f16x8*)&As[r * 32 + half * 16 + 8] = h1;
  }
  __syncthreads();

  int wr = w >> 1, wc = w & 1;
  f16x8 af[4], bf[4];
#pragma unroll
  for (int mi = 0; mi < 4; ++mi)
    af[mi] = *(const f16x8*)&As[(wr * 64 + mi * 16 + l15) * 32 + q * 8];
#pragma unroll
  for (int ni = 0; ni < 4; ++ni)
    bf[ni] = *(const f16x8*)(v1t + (size_t)(n0 + wc * 64 + ni * 16 + l15) * 32 + q * 8);

  f32x4 acc[4][4] = {};
#pragma unroll
  for (int mi = 0; mi < 4; ++mi)
#pragma unroll
    for (int ni = 0; ni < 4; ++ni)
      acc[mi][ni] = __builtin_amdgcn_mfma_f32_16x16x32_f16(af[mi], bf[ni], acc[mi][ni], 0, 0, 0);

#pragma unroll
  for (int ni = 0; ni < 4; ++ni) {
    int col = n0 + wc * 64 + ni * 16 + l15;
    float sg = sigmoid_fast(g1[col >> 5]);
    float bias = b1[col];
#pragma unroll
    for (int mi = 0; mi < 4; ++mi)
#pragma unroll
      for (int r = 0; r < 4; ++r) {
        int row = m0 + wr * 64 + mi * 16 + q * 4 + r;
        x1[(size_t)row * 1024 + col] = (_Float16)(tanh_fast(acc[mi][ni][r] + bias) * sg);
      }
  }
}

// ---------------- K2: ripple layer 2 (the big GEMM) ----------------
// x2[b,u] = tanh( sum_d x1[b,d]*V2t[u,d] + b2[u] ) * sigmoid(g2[u>>5])
__global__ __launch_bounds__(256) void k2_ripple2(
    const _Float16* __restrict__ x1, const _Float16* __restrict__ v2t,
    const float* __restrict__ b2, const float* __restrict__ g2,
    _Float16* __restrict__ x2) {
  __shared__ __align__(16) _Float16 As[128 * 32];
  __shared__ __align__(16) _Float16 Bs[128 * 32];
  int bn = blockIdx.x, bm = blockIdx.y;
  int t = threadIdx.x, w = t >> 6, l = t & 63, q = l >> 4, l15 = l & 15;
  int n0 = bn * 128, m0 = bm * 128;
  int wr = w >> 1, wc = w & 1;
  f32x4 acc[4][4] = {};

  int lrow = l >> 2;          // 0..15
  int lpart = (l & 3) * 8;    // element offset within 32-k row
  const _Float16* aBase = x1  + (size_t)(m0 + w * 32 + lrow) * 1024 + lpart;
  const _Float16* bBase = v2t + (size_t)(n0 + w * 32 + lrow) * 1024 + lpart;
  _Float16* aL = As + (w * 32) * 32;
  _Float16* bL = Bs + (w * 32) * 32;

  for (int kt = 0; kt < 32; ++kt) {
    __syncthreads();
    int ko = kt * 32;
    async16(aBase + ko,             aL);
    async16(aBase + ko + 16 * 1024, aL + 16 * 32);
    async16(bBase + ko,             bL);
    async16(bBase + ko + 16 * 1024, bL + 16 * 32);
    __builtin_amdgcn_s_waitcnt(0);
    __syncthreads();
    f16x8 af[4], bf[4];
#pragma unroll
    for (int mi = 0; mi < 4; ++mi)
      af[mi] = *(const f16x8*)&As[(wr * 64 + mi * 16 + l15) * 32 + q * 8];
#pragma unroll
    for (int ni = 0; ni < 4; ++ni)
      bf[ni] = *(const f16x8*)&Bs[(wc * 64 + ni * 16 + l15) * 32 + q * 8];
#pragma unroll
    for (int mi = 0; mi < 4; ++mi)
#pragma unroll
      for (int ni = 0; ni < 4; ++ni)
        acc[mi][ni] = __builtin_amdgcn_mfma_f32_16x16x32_f16(af[mi], bf[ni], acc[mi][ni], 0, 0, 0);
  }

#pragma unroll
  for (int ni = 0; ni < 4; ++ni) {
    int col = n0 + wc * 64 + ni * 16 + l15;
    float sg = sigmoid_fast(g2[col >> 5]);
    float bias = b2[col];
#pragma unroll
    for (int mi = 0; mi < 4; ++mi)
#pragma unroll
      for (int r = 0; r < 4; ++r) {
        int row = m0 + wr * 64 + mi * 16 + q * 4 + r;
        x2[(size_t)row * 1024 + col] = (_Float16)(tanh_fast(acc[mi][ni][r] + bias) * sg);
      }
  }
}

// ---------------- K3: fused q-network head ----------------
__global__ __launch_bounds__(256) void k3_head(
    const _Float16* __restrict__ x2, const _Float16* __restrict__ t1t,
    const _Float16* __restrict__ t2t,
    const float* __restrict__ bq1, const float* __restrict__ ln1g, const float* __restrict__ ln1b,
    const float* __restrict__ bq2, const float* __restrict__ ln2g, const float* __restrict__ ln2b,
    const float* __restrict__ wq3, const float* __restrict__ bq3,
    float* __restrict__ out) {
  __shared__ __align__(16) _Float16 Ast[64 * 32];     // 4 KB
  __shared__ __align__(16) _Float16 y1h[64 * 264];    // 33 KB, padded stride
  __shared__ float redA[64 * 4], redB[64 * 4];
  __shared__ float meanv[64], rstdv[64];
  int bm = blockIdx.x;
  int t = threadIdx.x, w = t >> 6, l = t & 63, q = l >> 4, l15 = l & 15;
  int m0 = bm * 64;

  // ---- GEMM3: [64 x 1024] @ [1024 x 256], wave w owns cols w*64..w*64+63
  f32x4 acc[4][4] = {};
  const _Float16* aBase = x2 + (size_t)(m0 + w * 16 + (l >> 2)) * 1024 + (l & 3) * 8;
  _Float16* aL = Ast + w * 512;
  const _Float16* bG = t1t + (size_t)(w * 64 + l15) * 1024 + q * 8;

  for (int kt = 0; kt < 32; ++kt) {
    __syncthreads();
    async16(aBase + kt * 32, aL);
    __builtin_amdgcn_s_waitcnt(0);
    __syncthreads();
    f16x8 af[4];
#pragma unroll
    for (int mi = 0; mi < 4; ++mi)
      af[mi] = *(const f16x8*)&Ast[(mi * 16 + l15) * 32 + q * 8];
#pragma unroll
    for (int ni = 0; ni < 4; ++ni) {
      f16x8 bf = *(const f16x8*)(bG + (size_t)ni * 16 * 1024 + kt * 32);
#pragma unroll
      for (int mi = 0; mi < 4; ++mi)
        acc[mi][ni] = __builtin_amdgcn_mfma_f32_16x16x32_f16(af[mi], bf, acc[mi][ni], 0, 0, 0);
    }
  }

  // bias + row-sum / row-sumsq over 256 cols
#pragma unroll
  for (int ni = 0; ni < 4; ++ni) {
    int col = w * 64 + ni * 16 + l15;
    float b = bq1[col];
#pragma unroll
    for (int mi = 0; mi < 4; ++mi)
#pragma unroll
      for (int r = 0; r < 4; ++r) acc[mi][ni][r] += b;
  }
#pragma unroll
  for (int mi = 0; mi < 4; ++mi)
#pragma unroll
    for (int r = 0; r < 4; ++r) {
      int row = mi * 16 + q * 4 + r;
      float s = 0.f, sq = 0.f;
#pragma unroll
      for (int ni = 0; ni < 4; ++ni) { float v = acc[mi][ni][r]; s += v; sq += v * v; }
#pragma unroll
      for (int off = 1; off < 16; off <<= 1) { s += __shfl_xor(s, off); sq += __shfl_xor(sq, off); }
      if (l15 == 0) { redA[row * 4 + w] = s; redB[row * 4 + w] = sq; }
    }
  __syncthreads();
  if (t < 64) {
    float s  = redA[t * 4] + redA[t * 4 + 1] + redA[t * 4 + 2] + redA[t * 4 + 3];
    float sq = redB[t * 4] + redB[t * 4 + 1] + redB[t * 4 + 2] + redB[t * 4 + 3];
    float mean = s * (1.0f / 256.0f);
    float var = sq * (1.0f / 256.0f) - mean * mean;
    meanv[t] = mean; rstdv[t] = rsqrtf(var + 1e-5f);
  }
  __syncthreads();
  // LN + relu -> y1h (fp16, A-layout, padded stride 264)
#pragma unroll
  for (int mi = 0; mi < 4; ++mi)
#pragma unroll
    for (int ni = 0; ni < 4; ++ni)
#pragma unroll
      for (int r = 0; r < 4; ++r) {
        int row = mi * 16 + q * 4 + r;
        int col = w * 64 + ni * 16 + l15;
        float y = (acc[mi][ni][r] - meanv[row]) * rstdv[row] * ln1g[col] + ln1b[col];
        y = fmaxf(y, 0.f);
        y1h[row * 264 + col] = (_Float16)y;
      }
  __syncthreads();

  // ---- GEMM4: [64 x 256] @ [256 x 128]; waves as 2(rows) x 2(cols)
  int wr = w >> 1, wc = w & 1;
  f32x4 a2[2][4] = {};
  for (int kt = 0; kt < 8; ++kt) {
    f16x8 af2[2];
#pragma unroll
    for (int mi = 0; mi < 2; ++mi)
      af2[mi] = *(const f16x8*)&y1h[(wr * 32 + mi * 16 + l15) * 264 + kt * 32 + q * 8];
#pragma unroll
    for (int ni = 0; ni < 4; ++ni) {
      f16x8 bf = *(const f16x8*)(t2t + (size_t)(wc * 64 + ni * 16 + l15) * 256 + kt * 32 + q * 8);
#pragma unroll
      for (int mi = 0; mi < 2; ++mi)
        a2[mi][ni] = __builtin_amdgcn_mfma_f32_16x16x32_f16(af2[mi], bf, a2[mi][ni], 0, 0, 0);
    }
  }
#pragma unroll
  for (int ni = 0; ni < 4; ++ni) {
    int col = wc * 64 + ni * 16 + l15;
    float b = bq2[col];
#pragma unroll
    for (int mi = 0; mi < 2; ++mi)
#pragma unroll
      for (int r = 0; r < 4; ++r) a2[mi][ni][r] += b;
  }
  __syncthreads();   // redA/redB reuse safe (all prior reads complete)
#pragma unroll
  for (int mi = 0; mi < 2; ++mi)
#pragma unroll
    for (int r = 0; r < 4; ++r) {
      int row = wr * 32 + mi * 16 + q * 4 + r;
      float s = 0.f, sq = 0.f;
#pragma unroll
      for (int ni = 0; ni < 4; ++ni) { float v = a2[mi][ni][r]; s += v; sq += v * v; }
#pragma unroll
      for (int off = 1; off < 16; off <<= 1) { s += __shfl_xor(s, off); sq += __shfl_xor(sq, off); }
      if (l15 == 0) { redA[row * 2 + wc] = s; redB[row * 2 + wc] = sq; }
    }
  __syncthreads();
  if (t < 64) {
    float s = redA[t * 2] + redA[t * 2 + 1];
    float sq = redB[t * 2] + redB[t * 2 + 1];
    float mean = s * (1.0f / 128.0f);
    float var = sq * (1.0f / 128.0f) - mean * mean;
    meanv[t] = mean; rstdv[t] = rsqrtf(var + 1e-5f);
  }
  __syncthreads();
  // LN + relu + dot(wq3)
#pragma unroll
  for (int mi = 0; mi < 2; ++mi)
#pragma unroll
    for (int r = 0; r < 4; ++r) {
      int row = wr * 32 + mi * 16 + q * 4 + r;
      float pr = 0.f;
#pragma unroll
      for (int ni = 0; ni < 4; ++ni) {
        int col = wc * 64 + ni * 16 + l15;
        float y = (a2[mi][ni][r] - meanv[row]) * rstdv[row] * ln2g[col] + ln2b[col];
        y = fmaxf(y, 0.f);
        pr += y * wq3[col];
      }
#pragma unroll
      for (int off = 1; off < 16; off <<= 1) pr += __shfl_xor(pr, off);
      if (l15 == 0) redA[row * 2 + wc] = pr;
    }
  __syncthreads();
  if (t < 64) out[m0 + t] = redA[t * 2] + redA[t * 2 + 1] + bq3[0];
}

// ---------------- launcher ----------------
extern "C" void kernel_launch(void* const* d_in, const int* in_sizes, int n_in,
                              void* d_out, int out_size, void* d_ws, size_t ws_size,
                              hipStream_t stream) {
  const float* state  = (const float*)d_in[0];
  const float* action = (const float*)d_in[1];
  const float* W1  = (const float*)d_in[2];
  const float* b1  = (const float*)d_in[3];
  const float* g1  = (const float*)d_in[4];
  const float* W2  = (const float*)d_in[5];
  const float* b2  = (const float*)d_in[6];
  const float* g2  = (const float*)d_in[7];
  const float* Wq1 = (const float*)d_in[8];
  const float* bq1 = (const float*)d_in[9];
  const float* ln1g = (const float*)d_in[10];
  const float* ln1b = (const float*)d_in[11];
  const float* Wq2 = (const float*)d_in[12];
  const float* bq2 = (const float*)d_in[13];
  const float* ln2g = (const float*)d_in[14];
  const float* ln2b = (const float*)d_in[15];
  const float* Wq3 = (const float*)d_in[16];
  const float* bq3 = (const float*)d_in[17];
  int B = in_sizes[0] / 24;

  char* ws = (char*)d_ws;
  _Float16* V1t = (_Float16*)(ws);
  _Float16* V2t = (_Float16*)(ws + 65536);
  _Float16* T1t = (_Float16*)(ws + 65536 + 2097152);
  _Float16* T2t = (_Float16*)(ws + 65536 + 2097152 + 524288);
  size_t woff = (65536 + 2097152 + 524288 + 65536 + 4095) & ~(size_t)4095;

  size_t avail = ws_size > woff ? ws_size - woff : 0;
  long rows = (long)(avail / 4096);     // x1 + x2, fp16, 1024 wide each
  if (rows > 32768) rows = 32768;       // keep slice L3-resident
  rows &= ~127L;
  if (rows < 128) rows = 128;
  int S = (int)rows;
  _Float16* x1 = (_Float16*)(ws + woff);
  _Float16* x2 = x1 + (size_t)S * 1024;

  transpose_cvt<<<dim3(1, 1, 32), 256, 0, stream>>>(W1, V1t, 32, 32);
  transpose_cvt<<<dim3(32, 1, 32), 256, 0, stream>>>(W2, V2t, 1024, 32);
  transpose_cvt<<<dim3(32, 8, 1), 256, 0, stream>>>(Wq1, T1t, 1024, 256);
  transpose_cvt<<<dim3(8, 4, 1), 256, 0, stream>>>(Wq2, T2t, 256, 128);

  for (int r0 = 0; r0 < B; r0 += S) {
    int Sc = S < (B - r0) ? S : (B - r0);
    k1_ripple1<<<dim3(8, Sc / 128), 256, 0, stream>>>(state, action, V1t, b1, g1, x1, r0);
    k2_ripple2<<<dim3(8, Sc / 128), 256, 0, stream>>>(x1, V2t, b2, g2, x2);
    k3_head<<<dim3(Sc / 64), 256, 0, stream>>>(x2, T1t, T2t, bq1, ln1g, ln1b,
                                               bq2, ln2g, ln2b, Wq3, bq3,
                                               (float*)d_out + r0);
  }
}

// Round 2
// 697.524 us; speedup vs baseline: 1.2321x; 1.2321x over previous
//
#include <hip/hip_runtime.h>
#include <hip/hip_bf16.h>

typedef _Float16 f16x8 __attribute__((ext_vector_type(8)));
typedef float f32x4 __attribute__((ext_vector_type(4)));

__device__ __forceinline__ void async16(const _Float16* g, _Float16* l) {
  __builtin_amdgcn_global_load_lds(
      (const __attribute__((address_space(1))) unsigned int*)g,
      (__attribute__((address_space(3))) unsigned int*)l, 16, 0, 0);
}

__device__ __forceinline__ float tanh_fast(float x) {
  float e = __expf(2.0f * x);
  return 1.0f - 2.0f * __builtin_amdgcn_rcpf(e + 1.0f);
}
__device__ __forceinline__ float sigmoid_fast(float x) {
  return __builtin_amdgcn_rcpf(1.0f + __expf(-x));
}

// ---------------- K0: transpose + fp32 -> fp16 convert ----------------
__global__ __launch_bounds__(256) void transpose_cvt(const float* __restrict__ in,
                                                     _Float16* __restrict__ out,
                                                     int R, int C) {
  __shared__ float tile[32][33];
  int z = blockIdx.z;
  in  += (size_t)z * R * C;
  out += (size_t)z * R * C;
  int r0 = blockIdx.x * 32, c0 = blockIdx.y * 32;
  int t = threadIdx.x;
  int cc = t & 31, rr8 = t >> 5;
#pragma unroll
  for (int p = 0; p < 4; ++p) {
    int r = rr8 + p * 8;
    tile[cc][r] = in[(size_t)(r0 + r) * C + c0 + cc];
  }
  __syncthreads();
  int rr = t & 31, cc8 = t >> 5;
#pragma unroll
  for (int p = 0; p < 4; ++p) {
    int c = cc8 + p * 8;
    out[(size_t)(c0 + c) * R + r0 + rr] = (_Float16)tile[c][rr];
  }
}

// ---------------- K1: ripple layer 1 ----------------
__global__ __launch_bounds__(256) void k1_ripple1(
    const float* __restrict__ state, const float* __restrict__ action,
    const _Float16* __restrict__ v1t, const float* __restrict__ b1,
    const float* __restrict__ g1, _Float16* __restrict__ x1, int gro) {
  __shared__ __align__(16) _Float16 As[128 * 40];   // padded stride 40 halfwords
  int bn = blockIdx.x, bm = blockIdx.y;
  int t = threadIdx.x, w = t >> 6, l = t & 63, q = l >> 4, l15 = l & 15;
  int n0 = bn * 128, m0 = bm * 128;

  {  // stage sa tile [128][32] fp16 (concat state|action)
    int r = t >> 1, half = t & 1;
    size_t grow = (size_t)(gro + m0 + r);
    float v[16];
    if (half == 0) {
      const float4* sp = (const float4*)(state + grow * 24);
      ((float4*)v)[0] = sp[0]; ((float4*)v)[1] = sp[1];
      ((float4*)v)[2] = sp[2]; ((float4*)v)[3] = sp[3];
    } else {
      const float4* sp = (const float4*)(state + grow * 24 + 16);
      ((float4*)v)[0] = sp[0]; ((float4*)v)[1] = sp[1];
      const float4* ap = (const float4*)(action + grow * 8);
      ((float4*)v)[2] = ap[0]; ((float4*)v)[3] = ap[1];
    }
    f16x8 h0, h1;
#pragma unroll
    for (int j = 0; j < 8; ++j) { h0[j] = (_Float16)v[j]; h1[j] = (_Float16)v[8 + j]; }
    *(f16x8*)&As[r * 40 + half * 16] = h0;
    *(f16x8*)&As[r * 40 + half * 16 + 8] = h1;
  }
  __syncthreads();

  int wr = w >> 1, wc = w & 1;
  f16x8 af[4], bf[4];
#pragma unroll
  for (int mi = 0; mi < 4; ++mi)
    af[mi] = *(const f16x8*)&As[(wr * 64 + mi * 16 + l15) * 40 + q * 8];
#pragma unroll
  for (int ni = 0; ni < 4; ++ni)
    bf[ni] = *(const f16x8*)(v1t + (size_t)(n0 + wc * 64 + ni * 16 + l15) * 32 + q * 8);

  f32x4 acc[4][4] = {};
#pragma unroll
  for (int mi = 0; mi < 4; ++mi)
#pragma unroll
    for (int ni = 0; ni < 4; ++ni)
      acc[mi][ni] = __builtin_amdgcn_mfma_f32_16x16x32_f16(af[mi], bf[ni], acc[mi][ni], 0, 0, 0);

#pragma unroll
  for (int ni = 0; ni < 4; ++ni) {
    int col = n0 + wc * 64 + ni * 16 + l15;
    float sg = sigmoid_fast(g1[col >> 5]);
    float bias = b1[col];
#pragma unroll
    for (int mi = 0; mi < 4; ++mi)
#pragma unroll
      for (int r = 0; r < 4; ++r) {
        int row = m0 + wr * 64 + mi * 16 + q * 4 + r;
        x1[(size_t)row * 1024 + col] = (_Float16)(tanh_fast(acc[mi][ni][r] + bias) * sg);
      }
  }
}

// ---------------- K2: ripple layer 2 (the big GEMM) ----------------
// Block tile 128(M) x 256(N), 4 waves as 2x2 of 64x128 wave tiles.
// XCD-affine block remap; XOR-swizzled LDS to kill 8-way conflicts.
__global__ __launch_bounds__(256, 2) void k2_ripple2(
    const _Float16* __restrict__ x1, const _Float16* __restrict__ v2t,
    const float* __restrict__ b2, const float* __restrict__ g2,
    _Float16* __restrict__ x2, int nbm) {
  __shared__ __align__(16) _Float16 As[128 * 32];   // 8 KB
  __shared__ __align__(16) _Float16 Bs[256 * 32];   // 16 KB
  int g = blockIdx.x;
  int bn, bm;
  if ((nbm & 7) == 0) {         // all 4 bn of one bm land on the same XCD,
    int x = g & 7, j = g >> 3;  // consecutively in that XCD's local order
    bn = j & 3; bm = x + 8 * (j >> 2);
  } else { bn = g & 3; bm = g >> 2; }
  int t = threadIdx.x, w = t >> 6, l = t & 63, q = l >> 4, l15 = l & 15;
  int n0 = bn * 256, m0 = bm * 128;
  int wr = w >> 1, wc = w & 1;
  f32x4 acc[4][8] = {};

  // staging: physical chunk c holds logical (row c>>2, part (c&3)^((c>>3)&3))
  int cA0 = t, cA1 = t + 256;
  const _Float16* aS0 = x1 + (size_t)(m0 + (cA0 >> 2)) * 1024 + ((cA0 & 3) ^ ((cA0 >> 3) & 3)) * 8;
  const _Float16* aS1 = x1 + (size_t)(m0 + (cA1 >> 2)) * 1024 + ((cA1 & 3) ^ ((cA1 >> 3) & 3)) * 8;
  _Float16* aD0 = As + cA0 * 8;
  _Float16* aD1 = As + cA1 * 8;
  const _Float16* bS[4]; _Float16* bD[4];
#pragma unroll
  for (int i = 0; i < 4; ++i) {
    int c = t + i * 256;
    bS[i] = v2t + (size_t)(n0 + (c >> 2)) * 1024 + ((c & 3) ^ ((c >> 3) & 3)) * 8;
    bD[i] = Bs + c * 8;
  }
  int qs = q ^ ((l15 >> 1) & 3);   // swizzled part for fragment reads

  for (int kt = 0; kt < 32; ++kt) {
    __syncthreads();
    int ko = kt * 32;
    async16(aS0 + ko, aD0);
    async16(aS1 + ko, aD1);
#pragma unroll
    for (int i = 0; i < 4; ++i) async16(bS[i] + ko, bD[i]);
    __builtin_amdgcn_s_waitcnt(0);
    __syncthreads();
    f16x8 af[4], bf[8];
#pragma unroll
    for (int mi = 0; mi < 4; ++mi)
      af[mi] = *(const f16x8*)&As[(wr * 64 + mi * 16 + l15) * 32 + qs * 8];
#pragma unroll
    for (int ni = 0; ni < 8; ++ni)
      bf[ni] = *(const f16x8*)&Bs[(wc * 128 + ni * 16 + l15) * 32 + qs * 8];
#pragma unroll
    for (int mi = 0; mi < 4; ++mi)
#pragma unroll
      for (int ni = 0; ni < 8; ++ni)
        acc[mi][ni] = __builtin_amdgcn_mfma_f32_16x16x32_f16(af[mi], bf[ni], acc[mi][ni], 0, 0, 0);
  }

#pragma unroll
  for (int ni = 0; ni < 8; ++ni) {
    int col = n0 + wc * 128 + ni * 16 + l15;
    float sg = sigmoid_fast(g2[col >> 5]);
    float bias = b2[col];
#pragma unroll
    for (int mi = 0; mi < 4; ++mi)
#pragma unroll
      for (int r = 0; r < 4; ++r) {
        int row = m0 + wr * 64 + mi * 16 + q * 4 + r;
        x2[(size_t)row * 1024 + col] = (_Float16)(tanh_fast(acc[mi][ni][r] + bias) * sg);
      }
  }
}

// ---------------- K3: fused q-network head ----------------
// GEMM3 now LDS-stages B (T1t tile) like k2 instead of per-kt global reads.
__global__ __launch_bounds__(256) void k3_head(
    const _Float16* __restrict__ x2, const _Float16* __restrict__ t1t,
    const _Float16* __restrict__ t2t,
    const float* __restrict__ bq1, const float* __restrict__ ln1g, const float* __restrict__ ln1b,
    const float* __restrict__ bq2, const float* __restrict__ ln2g, const float* __restrict__ ln2b,
    const float* __restrict__ wq3, const float* __restrict__ bq3,
    float* __restrict__ out) {
  __shared__ __align__(16) _Float16 Ast[64 * 32];     // 4 KB
  __shared__ __align__(16) _Float16 Bst[256 * 32];    // 16 KB
  __shared__ __align__(16) _Float16 y1h[64 * 264];    // 33 KB
  __shared__ float redA[64 * 4], redB[64 * 4];
  __shared__ float meanv[64], rstdv[64];
  int bm = blockIdx.x;
  int t = threadIdx.x, w = t >> 6, l = t & 63, q = l >> 4, l15 = l & 15;
  int m0 = bm * 64;
  int qs = q ^ ((l15 >> 1) & 3);

  // ---- GEMM3: [64 x 1024] @ [1024 x 256]; wave w owns cols w*64..w*64+63
  f32x4 acc[4][4] = {};
  int cA = t;
  const _Float16* aS = x2 + (size_t)(m0 + (cA >> 2)) * 1024 + ((cA & 3) ^ ((cA >> 3) & 3)) * 8;
  _Float16* aD = Ast + cA * 8;
  const _Float16* bS[4]; _Float16* bD[4];
#pragma unroll
  for (int i = 0; i < 4; ++i) {
    int c = t + i * 256;
    bS[i] = t1t + (size_t)(c >> 2) * 1024 + ((c & 3) ^ ((c >> 3) & 3)) * 8;
    bD[i] = Bst + c * 8;
  }

  for (int kt = 0; kt < 32; ++kt) {
    __syncthreads();
    int ko = kt * 32;
    async16(aS + ko, aD);
#pragma unroll
    for (int i = 0; i < 4; ++i) async16(bS[i] + ko, bD[i]);
    __builtin_amdgcn_s_waitcnt(0);
    __syncthreads();
    f16x8 af[4], bf[4];
#pragma unroll
    for (int mi = 0; mi < 4; ++mi)
      af[mi] = *(const f16x8*)&Ast[(mi * 16 + l15) * 32 + qs * 8];
#pragma unroll
    for (int ni = 0; ni < 4; ++ni)
      bf[ni] = *(const f16x8*)&Bst[(w * 64 + ni * 16 + l15) * 32 + qs * 8];
#pragma unroll
    for (int mi = 0; mi < 4; ++mi)
#pragma unroll
      for (int ni = 0; ni < 4; ++ni)
        acc[mi][ni] = __builtin_amdgcn_mfma_f32_16x16x32_f16(af[mi], bf[ni], acc[mi][ni], 0, 0, 0);
  }

  // bias + row-sum / row-sumsq over 256 cols
#pragma unroll
  for (int ni = 0; ni < 4; ++ni) {
    int col = w * 64 + ni * 16 + l15;
    float b = bq1[col];
#pragma unroll
    for (int mi = 0; mi < 4; ++mi)
#pragma unroll
      for (int r = 0; r < 4; ++r) acc[mi][ni][r] += b;
  }
#pragma unroll
  for (int mi = 0; mi < 4; ++mi)
#pragma unroll
    for (int r = 0; r < 4; ++r) {
      int row = mi * 16 + q * 4 + r;
      float s = 0.f, sq = 0.f;
#pragma unroll
      for (int ni = 0; ni < 4; ++ni) { float v = acc[mi][ni][r]; s += v; sq += v * v; }
#pragma unroll
      for (int off = 1; off < 16; off <<= 1) { s += __shfl_xor(s, off); sq += __shfl_xor(sq, off); }
      if (l15 == 0) { redA[row * 4 + w] = s; redB[row * 4 + w] = sq; }
    }
  __syncthreads();
  if (t < 64) {
    float s  = redA[t * 4] + redA[t * 4 + 1] + redA[t * 4 + 2] + redA[t * 4 + 3];
    float sq = redB[t * 4] + redB[t * 4 + 1] + redB[t * 4 + 2] + redB[t * 4 + 3];
    float mean = s * (1.0f / 256.0f);
    float var = sq * (1.0f / 256.0f) - mean * mean;
    meanv[t] = mean; rstdv[t] = rsqrtf(var + 1e-5f);
  }
  __syncthreads();
  // LN + relu -> y1h (fp16, A-layout, padded stride 264)
#pragma unroll
  for (int mi = 0; mi < 4; ++mi)
#pragma unroll
    for (int ni = 0; ni < 4; ++ni)
#pragma unroll
      for (int r = 0; r < 4; ++r) {
        int row = mi * 16 + q * 4 + r;
        int col = w * 64 + ni * 16 + l15;
        float y = (acc[mi][ni][r] - meanv[row]) * rstdv[row] * ln1g[col] + ln1b[col];
        y = fmaxf(y, 0.f);
        y1h[row * 264 + col] = (_Float16)y;
      }
  __syncthreads();

  // ---- GEMM4: [64 x 256] @ [256 x 128]; waves as 2(rows) x 2(cols)
  int wr = w >> 1, wc = w & 1;
  f32x4 a2[2][4] = {};
  for (int kt = 0; kt < 8; ++kt) {
    f16x8 af2[2];
#pragma unroll
    for (int mi = 0; mi < 2; ++mi)
      af2[mi] = *(const f16x8*)&y1h[(wr * 32 + mi * 16 + l15) * 264 + kt * 32 + q * 8];
#pragma unroll
    for (int ni = 0; ni < 4; ++ni) {
      f16x8 bf = *(const f16x8*)(t2t + (size_t)(wc * 64 + ni * 16 + l15) * 256 + kt * 32 + q * 8);
#pragma unroll
      for (int mi = 0; mi < 2; ++mi)
        a2[mi][ni] = __builtin_amdgcn_mfma_f32_16x16x32_f16(af2[mi], bf, a2[mi][ni], 0, 0, 0);
    }
  }
#pragma unroll
  for (int ni = 0; ni < 4; ++ni) {
    int col = wc * 64 + ni * 16 + l15;
    float b = bq2[col];
#pragma unroll
    for (int mi = 0; mi < 2; ++mi)
#pragma unroll
      for (int r = 0; r < 4; ++r) a2[mi][ni][r] += b;
  }
  __syncthreads();
#pragma unroll
  for (int mi = 0; mi < 2; ++mi)
#pragma unroll
    for (int r = 0; r < 4; ++r) {
      int row = wr * 32 + mi * 16 + q * 4 + r;
      float s = 0.f, sq = 0.f;
#pragma unroll
      for (int ni = 0; ni < 4; ++ni) { float v = a2[mi][ni][r]; s += v; sq += v * v; }
#pragma unroll
      for (int off = 1; off < 16; off <<= 1) { s += __shfl_xor(s, off); sq += __shfl_xor(sq, off); }
      if (l15 == 0) { redA[row * 2 + wc] = s; redB[row * 2 + wc] = sq; }
    }
  __syncthreads();
  if (t < 64) {
    float s = redA[t * 2] + redA[t * 2 + 1];
    float sq = redB[t * 2] + redB[t * 2 + 1];
    float mean = s * (1.0f / 128.0f);
    float var = sq * (1.0f / 128.0f) - mean * mean;
    meanv[t] = mean; rstdv[t] = rsqrtf(var + 1e-5f);
  }
  __syncthreads();
  // LN + relu + dot(wq3)
#pragma unroll
  for (int mi = 0; mi < 2; ++mi)
#pragma unroll
    for (int r = 0; r < 4; ++r) {
      int row = wr * 32 + mi * 16 + q * 4 + r;
      float pr = 0.f;
#pragma unroll
      for (int ni = 0; ni < 4; ++ni) {
        int col = wc * 64 + ni * 16 + l15;
        float y = (a2[mi][ni][r] - meanv[row]) * rstdv[row] * ln2g[col] + ln2b[col];
        y = fmaxf(y, 0.f);
        pr += y * wq3[col];
      }
#pragma unroll
      for (int off = 1; off < 16; off <<= 1) pr += __shfl_xor(pr, off);
      if (l15 == 0) redA[row * 2 + wc] = pr;
    }
  __syncthreads();
  if (t < 64) out[m0 + t] = redA[t * 2] + redA[t * 2 + 1] + bq3[0];
}

// ---------------- launcher ----------------
extern "C" void kernel_launch(void* const* d_in, const int* in_sizes, int n_in,
                              void* d_out, int out_size, void* d_ws, size_t ws_size,
                              hipStream_t stream) {
  const float* state  = (const float*)d_in[0];
  const float* action = (const float*)d_in[1];
  const float* W1  = (const float*)d_in[2];
  const float* b1  = (const float*)d_in[3];
  const float* g1  = (const float*)d_in[4];
  const float* W2  = (const float*)d_in[5];
  const float* b2  = (const float*)d_in[6];
  const float* g2  = (const float*)d_in[7];
  const float* Wq1 = (const float*)d_in[8];
  const float* bq1 = (const float*)d_in[9];
  const float* ln1g = (const float*)d_in[10];
  const float* ln1b = (const float*)d_in[11];
  const float* Wq2 = (const float*)d_in[12];
  const float* bq2 = (const float*)d_in[13];
  const float* ln2g = (const float*)d_in[14];
  const float* ln2b = (const float*)d_in[15];
  const float* Wq3 = (const float*)d_in[16];
  const float* bq3 = (const float*)d_in[17];
  int B = in_sizes[0] / 24;

  char* ws = (char*)d_ws;
  _Float16* V1t = (_Float16*)(ws);
  _Float16* V2t = (_Float16*)(ws + 65536);
  _Float16* T1t = (_Float16*)(ws + 65536 + 2097152);
  _Float16* T2t = (_Float16*)(ws + 65536 + 2097152 + 524288);
  size_t woff = (65536 + 2097152 + 524288 + 65536 + 4095) & ~(size_t)4095;

  size_t avail = ws_size > woff ? ws_size - woff : 0;
  long rows = (long)(avail / 4096);
  if (rows > 32768) rows = 32768;
  rows &= ~127L;
  if (rows < 128) rows = 128;
  int S = (int)rows;
  _Float16* x1 = (_Float16*)(ws + woff);
  _Float16* x2 = x1 + (size_t)S * 1024;

  transpose_cvt<<<dim3(1, 1, 32), 256, 0, stream>>>(W1, V1t, 32, 32);
  transpose_cvt<<<dim3(32, 1, 32), 256, 0, stream>>>(W2, V2t, 1024, 32);
  transpose_cvt<<<dim3(32, 8, 1), 256, 0, stream>>>(Wq1, T1t, 1024, 256);
  transpose_cvt<<<dim3(8, 4, 1), 256, 0, stream>>>(Wq2, T2t, 256, 128);

  for (int r0 = 0; r0 < B; r0 += S) {
    int Sc = S < (B - r0) ? S : (B - r0);
    int nbm = Sc / 128;
    k1_ripple1<<<dim3(8, nbm), 256, 0, stream>>>(state, action, V1t, b1, g1, x1, r0);
    k2_ripple2<<<dim3(4 * nbm), 256, 0, stream>>>(x1, V2t, b2, g2, x2, nbm);
    k3_head<<<dim3(Sc / 64), 256, 0, stream>>>(x2, T1t, T2t, bq1, ln1g, ln1b,
                                               bq2, ln2g, ln2b, Wq3, bq3,
                                               (float*)d_out + r0);
  }
}